// Round 15
// baseline (286.136 us; speedup 1.0000x reference)
//
#include <hip/hip_runtime.h>
#include <hip/hip_cooperative_groups.h>
#include <math.h>

// ---------------------------------------------------------------------------
// TACE (MACE-style equivariant GNN) forward on MI355X.
// N=5000 nodes, E=80000 edges, C=64, 2 layers, ranks 0..3 (dims 1,3,9,27).
//
// R15 = R13 (best, 112.9us) + CSR chain fused into ONE cooperative kernel:
//   k_csr: {zero, edge-basis+hist, 3-level scan, scatter, sort+perm}
//   separated by grid.sync(). 5 dispatches total (was 8).
// R14's gather_hj reverted (regression: k_node isn't latency-bound).
// Numerics identical (absmax ~4.9e-4).
// ---------------------------------------------------------------------------

namespace cg = cooperative_groups;

#define PI_F 3.14159265358979323846f
#define LOG2E_F 1.44269504088896340736f

typedef _Float16 f16x8 __attribute__((ext_vector_type(8)));
typedef float f32x4 __attribute__((ext_vector_type(4)));

union FU { uint4 u; f16x8 h; };

__device__ __forceinline__ float silu_f(float x) {
    float e = __builtin_amdgcn_exp2f(-LOG2E_F * x);
    return x * __builtin_amdgcn_rcpf(1.0f + e);
}

__device__ __forceinline__ uint pack2_f16(float a, float b) {
    return __builtin_bit_cast(uint, __builtin_amdgcn_cvt_pkrtz(a, b));
}

__device__ __forceinline__ float unpk_f16(uint u, int hi) {
    unsigned short s = hi ? (unsigned short)(u >> 16) : (unsigned short)(u & 0xffff);
    return (float)__builtin_bit_cast(_Float16, s);
}

// ---------------- setup: weight prep + embed ----------------
__global__ void k_setup(const float* __restrict__ rw1,   // [2,8,64]
                        const float* __restrict__ rw2,   // [2,64,64]
                        const float* __restrict__ rw3,   // [2,64,64]
                        const float* __restrict__ rw4,   // [2,64,256]
                        uint* __restrict__ Wf1, uint* __restrict__ Wf2,
                        uint* __restrict__ Wf3, uint* __restrict__ Wf4,
                        const int* __restrict__ species,
                        const float* __restrict__ embw,
                        float* __restrict__ h0,
                        int NC)
{
    int tid = blockIdx.x * blockDim.x + threadIdx.x;
    if (tid < NC) {
        int n = tid >> 6, c = tid & 63;
        h0[tid] = embw[species[n]*64 + c];
    }
    if (tid < 2048) {
        int reg = tid & 3, lane = (tid >> 2) & 63, ot = (tid >> 8) & 3, l = tid >> 10;
        int out = 16*ot + (lane & 15);
        int k   = 8*(lane >> 4) + 2*reg;
        float lo = (k   < 8) ? rw1[l*512 + k*64 + out]     : 0.0f;
        float hi = (k+1 < 8) ? rw1[l*512 + (k+1)*64 + out] : 0.0f;
        Wf1[tid] = pack2_f16(lo, hi);
    }
    if (tid >= 2048 && tid < 2048 + 4096) {
        int t = tid - 2048;
        int reg = t & 3, lane = (t >> 2) & 63, kt = (t >> 8) & 1, ot = (t >> 9) & 3, l = t >> 11;
        int out = 16*ot + (lane & 15);
        int k   = 32*kt + 8*(lane >> 4) + 2*reg;
        Wf2[t] = pack2_f16(rw2[l*4096 + k*64 + out], rw2[l*4096 + (k+1)*64 + out]);
    }
    if (tid >= 6144 && tid < 6144 + 4096) {
        int t = tid - 6144;
        int reg = t & 3, lane = (t >> 2) & 63, kt = (t >> 8) & 1, ot = (t >> 9) & 3, l = t >> 11;
        int out = 16*ot + (lane & 15);
        int k   = 32*kt + 8*(lane >> 4) + 2*reg;
        Wf3[t] = pack2_f16(rw3[l*4096 + k*64 + out], rw3[l*4096 + (k+1)*64 + out]);
    }
    if (tid >= 10240 && tid < 10240 + 16384) {
        int t = tid - 10240;
        int reg = t & 3, lane = (t >> 2) & 63, kt = (t >> 8) & 1, ot = (t >> 9) & 15, l = t >> 13;
        int out = 16*ot + (lane & 15);
        int k   = 32*kt + 8*(lane >> 4) + 2*reg;
        Wf4[t] = pack2_f16(rw4[l*16384 + k*256 + out], rw4[l*16384 + (k+1)*256 + out]);
    }
}

// ---------------- cooperative CSR build ----------------
// Phases: 0 zero | 1 edge basis + hist | 2 scan (3-level) | 3 scatter |
// 4 wave sort + perm. grid.sync() between phases. G blocks x 256 threads.
__global__ __launch_bounds__(256) void k_csr(
    const float* __restrict__ ev,
    const int* __restrict__ recv,
    const int* __restrict__ senders,
    uint*  __restrict__ rbh,        // [E,4]
    float* __restrict__ rhat4,      // [E,4]
    int* __restrict__ counts,
    int* __restrict__ cursor,
    int* __restrict__ offsets,      // [N+1]
    int* __restrict__ elist,        // [E]
    int* __restrict__ blocksum,     // [G]
    int* __restrict__ eslot,        // [E]
    int* __restrict__ csr_send,     // [E]
    float* __restrict__ csr_rhat,   // [E,4]
    int N, int E)
{
    cg::grid_group grid = cg::this_grid();
    __shared__ int red[256];
    int tid  = blockIdx.x * blockDim.x + threadIdx.x;
    int nthr = gridDim.x * blockDim.x;
    int G    = gridDim.x;
    int chunk = (N + G - 1) / G;

    // ---- phase 0: zero counts/cursor ----
    for (int i = tid; i < N; i += nthr) { counts[i] = 0; cursor[i] = 0; }
    grid.sync();

    // ---- phase 1: edge basis + histogram ----
    for (int e = tid; e < E; e += nthr) {
        float vx = ev[3*e+0], vy = ev[3*e+1], vz = ev[3*e+2];
        float r2 = vx*vx + vy*vy + vz*vz + 1e-12f;
        float r  = sqrtf(r2);
        float x  = r * 0.2f;
        float x2 = x*x;
        float x5 = x2*x2*x;
        float env = 1.0f + x5*(-21.0f + x*(35.0f - 15.0f*x));
        if (x >= 1.0f) env = 0.0f;
        float pref = 0.632455532033675866f / r * env;
        float pix  = PI_F * x;
        float bas[8];
        #pragma unroll
        for (int k = 0; k < 8; ++k) bas[k] = pref * __sinf((float)(k+1) * pix);
        uint* o = rbh + (size_t)e*4;
        #pragma unroll
        for (int k = 0; k < 4; ++k) o[k] = pack2_f16(bas[2*k], bas[2*k+1]);
        float ir = 1.0f / r;
        float4 rh;
        rh.x = vx*ir; rh.y = vy*ir; rh.z = vz*ir; rh.w = 0.0f;
        *(float4*)(rhat4 + (size_t)e*4) = rh;
        atomicAdd(&counts[recv[e]], 1);
    }
    grid.sync();

    // ---- phase 2a: per-block chunk sums ----
    {
        int start = blockIdx.x * chunk;
        int stop  = min(start + chunk, N);
        int v = 0;
        for (int i = start + (int)threadIdx.x; i < stop; i += 256) v += counts[i];
        red[threadIdx.x] = v;
        __syncthreads();
        for (int off = 128; off > 0; off >>= 1) {
            if (threadIdx.x < (unsigned)off) red[threadIdx.x] += red[threadIdx.x + off];
            __syncthreads();
        }
        if (threadIdx.x == 0) blocksum[blockIdx.x] = red[0];
    }
    grid.sync();

    // ---- phase 2b: block 0 exclusive-scans blocksum (G <= 256) ----
    if (blockIdx.x == 0) {
        int t = threadIdx.x;
        int v = (t < G) ? blocksum[t] : 0;
        red[t] = v;
        __syncthreads();
        for (int off = 1; off < 256; off <<= 1) {
            int add = (t >= (unsigned)off) ? red[t - off] : 0;
            __syncthreads();
            red[t] += add;
            __syncthreads();
        }
        if (t < G) blocksum[t] = (t == 0) ? 0 : red[t-1];
        if (t == 0) offsets[N] = E;
    }
    grid.sync();

    // ---- phase 2c: per-block serial prefix within chunk ----
    if (threadIdx.x == 0) {
        int start = blockIdx.x * chunk;
        int stop  = min(start + chunk, N);
        int run = blocksum[blockIdx.x];
        for (int i = start; i < stop; ++i) { offsets[i] = run; run += counts[i]; }
    }
    grid.sync();

    // ---- phase 3: scatter ----
    for (int e = tid; e < E; e += nthr) {
        int r = recv[e];
        int p = atomicAdd(&cursor[r], 1);
        elist[offsets[r] + p] = e;
    }
    grid.sync();

    // ---- phase 4: wave sort + perm (grid-stride over nodes) ----
    {
        int lane   = threadIdx.x & 63;
        int wid    = (blockIdx.x * 4) + (threadIdx.x >> 6);
        int nwaves = G * 4;
        for (int node = wid; node < N; node += nwaves) {
            int beg = offsets[node], end = offsets[node+1];
            int d = end - beg;
            if (d <= 0) continue;
            if (d <= 64) {
                int v = (lane < d) ? elist[beg + lane] : 0x7fffffff;
                int rank = 0;
                #pragma unroll 8
                for (int j = 0; j < 64; ++j) {
                    int vj = __shfl(v, j, 64);
                    rank += (vj < v) ? 1 : 0;
                }
                if (lane < d) {
                    int slot = beg + rank;
                    eslot[v] = slot;
                    csr_send[slot] = senders[v];
                    *(float4*)(csr_rhat + (size_t)slot*4) = *(const float4*)(rhat4 + (size_t)v*4);
                }
            } else {
                if (lane == 0) {
                    for (int i = beg + 1; i < end; ++i) {
                        int v = elist[i];
                        int j = i - 1;
                        while (j >= beg && elist[j] > v) { elist[j+1] = elist[j]; --j; }
                        elist[j+1] = v;
                    }
                    for (int s = beg; s < end; ++s) {
                        int e = elist[s];
                        eslot[e] = s;
                        csr_send[s] = senders[e];
                        *(float4*)(csr_rhat + (size_t)s*4) = *(const float4*)(rhat4 + (size_t)e*4);
                    }
                }
            }
        }
    }
}

// ---------------- radial MLP via MFMA: 32 edges/wave, weight reuse x2 ------
__global__ __launch_bounds__(128) void k_mlp_mfma(
    const uint* __restrict__ rbh,    // [E,4] u32 (8 f16), edge order
    const uint* __restrict__ Wf1, const uint* __restrict__ Wf2,
    const uint* __restrict__ Wf3, const uint* __restrict__ Wf4,
    const int* __restrict__ eslot,   // [E] edge -> CSR slot
    uint* __restrict__ Rpk,          // [2,E,128] u32, rank-interleaved, slot order
    int E, int tiles)                // tiles = ceil(E/32)
{
    __shared__ __align__(16) uint Hl[2][32][132];
    int lane = threadIdx.x & 63;
    int w    = threadIdx.x >> 6;
    int wid  = blockIdx.x * 2 + w;
    if (wid >= 2 * tiles) return;
    int l    = wid / tiles;
    int tile = wid % tiles;
    int e0   = tile * 32;

    uint (*H)[132] = Hl[w];
    int er = lane & 15;
    int kb = lane >> 4;

    f32x4 zero4 = {0.f, 0.f, 0.f, 0.f};

    // ---- stage 1 ----
    FU b0, b1;
    b0.u = make_uint4(0,0,0,0);
    b1.u = make_uint4(0,0,0,0);
    if (kb == 0) {
        int ea = e0 + er, eb = e0 + 16 + er;
        if (ea < E) b0.u = *(const uint4*)(rbh + (size_t)ea*4);
        if (eb < E) b1.u = *(const uint4*)(rbh + (size_t)eb*4);
    }
    f32x4 d0[4], d1[4];
    #pragma unroll
    for (int ot = 0; ot < 4; ++ot) {
        FU a;
        a.u = *(const uint4*)(Wf1 + ((size_t)(l*4 + ot)*64 + lane)*4);
        d0[ot] = __builtin_amdgcn_mfma_f32_16x16x32_f16(a.h, b0.h, zero4, 0, 0, 0);
        d1[ot] = __builtin_amdgcn_mfma_f32_16x16x32_f16(a.h, b1.h, zero4, 0, 0, 0);
    }
    #pragma unroll
    for (int ot = 0; ot < 4; ++ot) {
        uint* dA = &H[er][8*ot + 2*kb];
        dA[0] = pack2_f16(silu_f(d0[ot][0]), silu_f(d0[ot][1]));
        dA[1] = pack2_f16(silu_f(d0[ot][2]), silu_f(d0[ot][3]));
        uint* dB = &H[16 + er][8*ot + 2*kb];
        dB[0] = pack2_f16(silu_f(d1[ot][0]), silu_f(d1[ot][1]));
        dB[1] = pack2_f16(silu_f(d1[ot][2]), silu_f(d1[ot][3]));
    }

    // ---- stages 2,3 ----
    const uint* Wfs[2] = { Wf2, Wf3 };
    #pragma unroll
    for (int s = 0; s < 2; ++s) {
        FU hA0, hA1, hB0, hB1;
        hA0.u = *(const uint4*)&H[er][4*kb];
        hA1.u = *(const uint4*)&H[er][16 + 4*kb];
        hB0.u = *(const uint4*)&H[16 + er][4*kb];
        hB1.u = *(const uint4*)&H[16 + er][16 + 4*kb];
        #pragma unroll
        for (int ot = 0; ot < 4; ++ot) {
            FU a;
            a.u = *(const uint4*)(Wfs[s] + ((size_t)((l*4 + ot)*2 + 0)*64 + lane)*4);
            d0[ot] = __builtin_amdgcn_mfma_f32_16x16x32_f16(a.h, hA0.h, zero4, 0, 0, 0);
            d1[ot] = __builtin_amdgcn_mfma_f32_16x16x32_f16(a.h, hB0.h, zero4, 0, 0, 0);
            a.u = *(const uint4*)(Wfs[s] + ((size_t)((l*4 + ot)*2 + 1)*64 + lane)*4);
            d0[ot] = __builtin_amdgcn_mfma_f32_16x16x32_f16(a.h, hA1.h, d0[ot], 0, 0, 0);
            d1[ot] = __builtin_amdgcn_mfma_f32_16x16x32_f16(a.h, hB1.h, d1[ot], 0, 0, 0);
        }
        #pragma unroll
        for (int ot = 0; ot < 4; ++ot) {
            uint* dA = &H[er][8*ot + 2*kb];
            dA[0] = pack2_f16(silu_f(d0[ot][0]), silu_f(d0[ot][1]));
            dA[1] = pack2_f16(silu_f(d0[ot][2]), silu_f(d0[ot][3]));
            uint* dB = &H[16 + er][8*ot + 2*kb];
            dB[0] = pack2_f16(silu_f(d1[ot][0]), silu_f(d1[ot][1]));
            dB[1] = pack2_f16(silu_f(d1[ot][2]), silu_f(d1[ot][3]));
        }
    }

    // ---- stage 4 ----
    FU hA0, hA1, hB0, hB1;
    hA0.u = *(const uint4*)&H[er][4*kb];
    hA1.u = *(const uint4*)&H[er][16 + 4*kb];
    hB0.u = *(const uint4*)&H[16 + er][4*kb];
    hB1.u = *(const uint4*)&H[16 + er][16 + 4*kb];
    #pragma unroll
    for (int ri = 0; ri < 4; ++ri) {
        #pragma unroll
        for (int otl = 0; otl < 4; ++otl) {
            int ot = ri*4 + otl;
            FU a;
            f32x4 dA, dB;
            a.u = *(const uint4*)(Wf4 + ((size_t)((l*16 + ot)*2 + 0)*64 + lane)*4);
            dA = __builtin_amdgcn_mfma_f32_16x16x32_f16(a.h, hA0.h, zero4, 0, 0, 0);
            dB = __builtin_amdgcn_mfma_f32_16x16x32_f16(a.h, hB0.h, zero4, 0, 0, 0);
            a.u = *(const uint4*)(Wf4 + ((size_t)((l*16 + ot)*2 + 1)*64 + lane)*4);
            dA = __builtin_amdgcn_mfma_f32_16x16x32_f16(a.h, hA1.h, dA, 0, 0, 0);
            dB = __builtin_amdgcn_mfma_f32_16x16x32_f16(a.h, hB1.h, dB, 0, 0, 0);
            int p = otl*8 + kb*2;
            H[er][(p  )*4 + ri] = pack2_f16(dA[0], dA[1]);
            H[er][(p+1)*4 + ri] = pack2_f16(dA[2], dA[3]);
            H[16 + er][(p  )*4 + ri] = pack2_f16(dB[0], dB[1]);
            H[16 + er][(p+1)*4 + ri] = pack2_f16(dB[2], dB[3]);
        }
    }
    #pragma unroll
    for (int it = 0; it < 16; ++it) {
        int f   = it*64 + lane;
        int row = f >> 5;
        int q4  = (f & 31) * 4;
        int eg  = e0 + row;
        if (eg < E) {
            int slot = eslot[eg];
            *(uint4*)(Rpk + ((size_t)l*E + slot)*128 + q4) = *(const uint4*)&H[row][q4];
        }
    }
}

// ---------------- node gather + contraction + mix + readout ----------------
__global__ __launch_bounds__(256) void k_node(
    const uint*  __restrict__ Rpk,     // [E,128] u32 this layer, slot order
    const float* __restrict__ h0,      // [N,64]
    const int*   __restrict__ csr_send,// [E] slot -> sender
    const float* __restrict__ csr_rhat,// [E,4] slot order
    const int*   __restrict__ offsets, // [N+1]
    const float* __restrict__ mixw,    // [4,64,64] (this layer)
    const float* __restrict__ readw,   // [64]      (this layer)
    float* __restrict__ h0n,           // [N,64]
    const float* __restrict__ eprev,   // [N] or null
    float* __restrict__ eout,          // [N]
    int N)
{
    int gtid = blockIdx.x * blockDim.x + threadIdx.x;
    int wave = gtid >> 6;
    int lane = threadIdx.x & 63;
    int w    = threadIdx.x >> 6;
    __shared__ float Bl[4][4][64];
    bool active = (wave < N);
    int n = active ? wave : 0;
    int half  = lane & 1;
    int cpair = lane >> 1;

    float a0 = 0.f;
    float a1[3]  = {0.f,0.f,0.f};
    float a2[6]  = {0.f,0.f,0.f,0.f,0.f,0.f};
    float a3[10] = {0.f,0.f,0.f,0.f,0.f,0.f,0.f,0.f,0.f,0.f};

    auto accum = [&](float x, float y, float z, float hj, uint4 qv) {
        float t0 = unpk_f16(qv.x, half) * hj;
        float t1 = unpk_f16(qv.y, half) * hj;
        float t2 = unpk_f16(qv.z, half) * hj;
        float t3 = unpk_f16(qv.w, half) * hj;
        a0 += t0;
        a1[0] = fmaf(t1, x, a1[0]);
        a1[1] = fmaf(t1, y, a1[1]);
        a1[2] = fmaf(t1, z, a1[2]);
        float qxx = x*x, qxy = x*y, qxz = x*z, qyy = y*y, qyz = y*z, qzz = z*z;
        a2[0] = fmaf(t2, qxx, a2[0]);
        a2[1] = fmaf(t2, qxy, a2[1]);
        a2[2] = fmaf(t2, qxz, a2[2]);
        a2[3] = fmaf(t2, qyy, a2[3]);
        a2[4] = fmaf(t2, qyz, a2[4]);
        a2[5] = fmaf(t2, qzz, a2[5]);
        float u0 = t3*qxx, u1 = t3*qxy, u3 = t3*qyy, u5 = t3*qzz;
        a3[0] = fmaf(u0, x, a3[0]);
        a3[1] = fmaf(u0, y, a3[1]);
        a3[2] = fmaf(u0, z, a3[2]);
        a3[3] = fmaf(u3, x, a3[3]);
        a3[4] = fmaf(u1, z, a3[4]);
        a3[5] = fmaf(u5, x, a3[5]);
        a3[6] = fmaf(u3, y, a3[6]);
        a3[7] = fmaf(u3, z, a3[7]);
        a3[8] = fmaf(u5, y, a3[8]);
        a3[9] = fmaf(u5, z, a3[9]);
    };

    if (active) {
        int beg = __builtin_amdgcn_readfirstlane(offsets[n]);
        int end = __builtin_amdgcn_readfirstlane(offsets[n+1]);
        int i = beg;
        for (; i + 4 <= end; i += 4) {
            int sn_[4]; float4 rh_[4]; float hj_[4]; uint4 q_[4];
            #pragma unroll
            for (int k = 0; k < 4; ++k) sn_[k] = csr_send[i+k];
            #pragma unroll
            for (int k = 0; k < 4; ++k) {
                rh_[k] = *(const float4*)(csr_rhat + (size_t)(i+k)*4);
                q_[k]  = *(const uint4*)(Rpk + (size_t)(i+k)*128 + cpair*4);
            }
            #pragma unroll
            for (int k = 0; k < 4; ++k) hj_[k] = h0[(size_t)sn_[k]*64 + lane];
            #pragma unroll
            for (int k = 0; k < 4; ++k)
                accum(rh_[k].x, rh_[k].y, rh_[k].z, hj_[k], q_[k]);
        }
        for (; i < end; ++i) {
            int snd = csr_send[i];
            float4 rh = *(const float4*)(csr_rhat + (size_t)i*4);
            uint4  qv = *(const uint4*)(Rpk + (size_t)i*128 + cpair*4);
            float  hj = h0[(size_t)snd*64 + lane];
            accum(rh.x, rh.y, rh.z, hj, qv);
        }
    }

    float B0 = a0 * 0.0625f;
    float s1 = a1[0]*a1[0] + a1[1]*a1[1] + a1[2]*a1[2];
    float B1 = s1 * (3.0f/256.0f);
    float s2 = a2[0]*a2[0] + a2[3]*a2[3] + a2[5]*a2[5]
             + 2.0f*(a2[1]*a2[1] + a2[2]*a2[2] + a2[4]*a2[4]);
    float B2 = s2 * (5.0f/256.0f);
    float s3 = a3[0]*a3[0] + a3[6]*a3[6] + a3[9]*a3[9]
             + 3.0f*(a3[1]*a3[1] + a3[2]*a3[2] + a3[3]*a3[3]
                   + a3[5]*a3[5] + a3[7]*a3[7] + a3[8]*a3[8])
             + 6.0f*a3[4]*a3[4];
    float B3 = s3 * (7.0f/256.0f);

    Bl[w][0][lane] = B0;
    Bl[w][1][lane] = B1;
    Bl[w][2][lane] = B2;
    Bl[w][3][lane] = B3;
    __syncthreads();

    if (active) {
        float acc = 0.0f;
        for (int ri = 0; ri < 4; ++ri) {
            #pragma unroll 8
            for (int j = 0; j < 64; ++j)
                acc = fmaf(Bl[w][ri][j], mixw[(ri*64 + j)*64 + lane], acc);
        }
        h0n[(size_t)n*64 + lane] = acc;

        float evl = acc * readw[lane];
        #pragma unroll
        for (int off = 1; off < 64; off <<= 1) evl += __shfl_xor(evl, off, 64);
        if (lane == 0) {
            float o = evl;
            if (eprev) o += eprev[n];
            eout[n] = o;
        }
    }
}

// ---------------------------------------------------------------------------
extern "C" void kernel_launch(void* const* d_in, const int* in_sizes, int n_in,
                              void* d_out, int out_size, void* d_ws, size_t ws_size,
                              hipStream_t stream)
{
    const int*   species   = (const int*)  d_in[0];
    const int*   senders   = (const int*)  d_in[1];
    const int*   receivers = (const int*)  d_in[2];
    const float* edge_vec  = (const float*)d_in[3];
    const float* embed_w   = (const float*)d_in[4];
    const float* rad_w1    = (const float*)d_in[5];
    const float* rad_w2    = (const float*)d_in[6];
    const float* rad_w3    = (const float*)d_in[7];
    const float* rad_w4    = (const float*)d_in[8];
    const float* mix_w     = (const float*)d_in[9];
    const float* read_w    = (const float*)d_in[10];

    int N = in_sizes[0];
    int E = in_sizes[1];
    float* out = (float*)d_out;

    char* ws = (char*)d_ws;
    size_t off = 0;
    auto alloc = [&](size_t bytes) -> char* {
        char* p = ws + off;
        off = (off + bytes + 255) & ~(size_t)255;
        return p;
    };
    uint*  rbh     = (uint*) alloc((size_t)E*4*sizeof(uint));
    float* rhat4   = (float*)alloc((size_t)E*4*sizeof(float));
    float* h0a     = (float*)alloc((size_t)N*64*sizeof(float));
    float* h0b     = (float*)alloc((size_t)N*64*sizeof(float));
    float* ener    = (float*)alloc((size_t)N*sizeof(float));
    int* counts    = (int*)alloc((size_t)N*sizeof(int));
    int* offsets   = (int*)alloc((size_t)(N+1)*sizeof(int));
    int* cursor    = (int*)alloc((size_t)N*sizeof(int));
    int* elist     = (int*)alloc((size_t)E*sizeof(int));
    int* eslot     = (int*)alloc((size_t)E*sizeof(int));
    int* csr_send  = (int*)alloc((size_t)E*sizeof(int));
    float* csr_rhat= (float*)alloc((size_t)E*4*sizeof(float));
    int* blocksum  = (int*)alloc(256*sizeof(int));
    uint* Wf1      = (uint*)alloc(2048*sizeof(uint));
    uint* Wf2      = (uint*)alloc(4096*sizeof(uint));
    uint* Wf3      = (uint*)alloc(4096*sizeof(uint));
    uint* Wf4      = (uint*)alloc(16384*sizeof(uint));
    uint* Rpk      = (uint*)alloc((size_t)2*E*128*sizeof(uint));

    int NC = N * 64;
    k_setup<<<(26624 + 255)/256 > (NC + 255)/256 ? (26624 + 255)/256 : (NC + 255)/256,
              256, 0, stream>>>(
        rad_w1, rad_w2, rad_w3, rad_w4, Wf1, Wf2, Wf3, Wf4,
        species, embed_w, h0a, NC);

    {
        int G = 256;
        void* args[] = {
            (void*)&edge_vec, (void*)&receivers, (void*)&senders,
            (void*)&rbh, (void*)&rhat4,
            (void*)&counts, (void*)&cursor, (void*)&offsets, (void*)&elist,
            (void*)&blocksum, (void*)&eslot, (void*)&csr_send, (void*)&csr_rhat,
            (void*)&N, (void*)&E
        };
        hipLaunchCooperativeKernel((const void*)k_csr, dim3(G), dim3(256),
                                   args, 0, stream);
    }

    int tiles = (E + 31) / 32;
    int waves = 2 * tiles;
    k_mlp_mfma<<<(waves + 1)/2, 128, 0, stream>>>(
        rbh, Wf1, Wf2, Wf3, Wf4, eslot, Rpk, E, tiles);

    float* hcur = h0a;
    float* hnxt = h0b;
    for (int l = 0; l < 2; ++l) {
        uint* Rl = Rpk + (size_t)l * E * 128;
        k_node<<<((size_t)N*64 + 255)/256, 256, 0, stream>>>(
            Rl, hcur, csr_send, csr_rhat, offsets,
            mix_w + (size_t)l*4*64*64,
            read_w + (size_t)l*64,
            hnxt,
            (l == 0) ? nullptr : ener,
            (l == 0) ? ener : out,
            N);
        float* tmp = hcur; hcur = hnxt; hnxt = tmp;
    }
}

// Round 16
// 106.876 us; speedup vs baseline: 2.6773x; 2.6773x over previous
//
#include <hip/hip_runtime.h>
#include <math.h>

// ---------------------------------------------------------------------------
// TACE (MACE-style equivariant GNN) forward on MI355X.
// N=5000 nodes, E=80000 edges, C=64, 2 layers, ranks 0..3 (dims 1,3,9,27).
//
// R16 = R13 (best, 112.9us) minus the edge sort:
//  - k_scatter_perm assigns CSR slots via atomics and writes the permutation
//    tables (eslot/csr_send/csr_rhat) directly. Per-node edge order becomes
//    arrival-order (non-deterministic), which only reassociates the fp32
//    per-node sums: ~1e-7 relative wiggle vs 1.4e-3 threshold (absmax 4.9e-4).
//  - k_sort_perm dispatch and elist eliminated: 7 dispatches.
// R15's cooperative grid.sync reverted (~30us/sync on 8-XCD MI355X).
// ---------------------------------------------------------------------------

#define PI_F 3.14159265358979323846f
#define LOG2E_F 1.44269504088896340736f

typedef _Float16 f16x8 __attribute__((ext_vector_type(8)));
typedef float f32x4 __attribute__((ext_vector_type(4)));

union FU { uint4 u; f16x8 h; };

__device__ __forceinline__ float silu_f(float x) {
    float e = __builtin_amdgcn_exp2f(-LOG2E_F * x);
    return x * __builtin_amdgcn_rcpf(1.0f + e);
}

__device__ __forceinline__ uint pack2_f16(float a, float b) {
    return __builtin_bit_cast(uint, __builtin_amdgcn_cvt_pkrtz(a, b));
}

__device__ __forceinline__ float unpk_f16(uint u, int hi) {
    unsigned short s = hi ? (unsigned short)(u >> 16) : (unsigned short)(u & 0xffff);
    return (float)__builtin_bit_cast(_Float16, s);
}

// ---------------- setup: weight prep + embed + zero counts/cursor ----------
__global__ void k_setup(const float* __restrict__ rw1,   // [2,8,64]
                        const float* __restrict__ rw2,   // [2,64,64]
                        const float* __restrict__ rw3,   // [2,64,64]
                        const float* __restrict__ rw4,   // [2,64,256]
                        uint* __restrict__ Wf1, uint* __restrict__ Wf2,
                        uint* __restrict__ Wf3, uint* __restrict__ Wf4,
                        const int* __restrict__ species,
                        const float* __restrict__ embw,
                        float* __restrict__ h0,
                        int* __restrict__ counts, int* __restrict__ cursor,
                        int N, int NC)
{
    int tid = blockIdx.x * blockDim.x + threadIdx.x;
    if (tid < N) { counts[tid] = 0; cursor[tid] = 0; }
    if (tid < NC) {
        int n = tid >> 6, c = tid & 63;
        h0[tid] = embw[species[n]*64 + c];
    }
    if (tid < 2048) {
        int reg = tid & 3, lane = (tid >> 2) & 63, ot = (tid >> 8) & 3, l = tid >> 10;
        int out = 16*ot + (lane & 15);
        int k   = 8*(lane >> 4) + 2*reg;
        float lo = (k   < 8) ? rw1[l*512 + k*64 + out]     : 0.0f;
        float hi = (k+1 < 8) ? rw1[l*512 + (k+1)*64 + out] : 0.0f;
        Wf1[tid] = pack2_f16(lo, hi);
    }
    if (tid >= 2048 && tid < 2048 + 4096) {
        int t = tid - 2048;
        int reg = t & 3, lane = (t >> 2) & 63, kt = (t >> 8) & 1, ot = (t >> 9) & 3, l = t >> 11;
        int out = 16*ot + (lane & 15);
        int k   = 32*kt + 8*(lane >> 4) + 2*reg;
        Wf2[t] = pack2_f16(rw2[l*4096 + k*64 + out], rw2[l*4096 + (k+1)*64 + out]);
    }
    if (tid >= 6144 && tid < 6144 + 4096) {
        int t = tid - 6144;
        int reg = t & 3, lane = (t >> 2) & 63, kt = (t >> 8) & 1, ot = (t >> 9) & 3, l = t >> 11;
        int out = 16*ot + (lane & 15);
        int k   = 32*kt + 8*(lane >> 4) + 2*reg;
        Wf3[t] = pack2_f16(rw3[l*4096 + k*64 + out], rw3[l*4096 + (k+1)*64 + out]);
    }
    if (tid >= 10240 && tid < 10240 + 16384) {
        int t = tid - 10240;
        int reg = t & 3, lane = (t >> 2) & 63, kt = (t >> 8) & 1, ot = (t >> 9) & 15, l = t >> 13;
        int out = 16*ot + (lane & 15);
        int k   = 32*kt + 8*(lane >> 4) + 2*reg;
        Wf4[t] = pack2_f16(rw4[l*16384 + k*256 + out], rw4[l*16384 + (k+1)*256 + out]);
    }
}

// ---------------- edge basis (rb f16, rhat) + receiver histogram ----------
__global__ void k_edge_basis(const float* __restrict__ ev,
                             const int* __restrict__ recv,
                             uint*  __restrict__ rbh,     // [E,4] u32 (8 f16)
                             float* __restrict__ rhat4,   // [E,4]
                             int*   __restrict__ counts,
                             int E)
{
    int e = blockIdx.x * blockDim.x + threadIdx.x;
    if (e >= E) return;
    float vx = ev[3*e+0], vy = ev[3*e+1], vz = ev[3*e+2];
    float r2 = vx*vx + vy*vy + vz*vz + 1e-12f;
    float r  = sqrtf(r2);
    float x  = r * 0.2f;                   // r / CUTOFF
    float x2 = x*x;
    float x5 = x2*x2*x;
    float env = 1.0f + x5*(-21.0f + x*(35.0f - 15.0f*x));
    if (x >= 1.0f) env = 0.0f;
    float pref = 0.632455532033675866f / r * env;   // sqrt(2/5)/r * env
    float pix  = PI_F * x;
    float bas[8];
    #pragma unroll
    for (int k = 0; k < 8; ++k) bas[k] = pref * __sinf((float)(k+1) * pix);
    uint* o = rbh + (size_t)e*4;
    #pragma unroll
    for (int k = 0; k < 4; ++k) o[k] = pack2_f16(bas[2*k], bas[2*k+1]);

    float ir = 1.0f / r;
    float4 rh;
    rh.x = vx*ir; rh.y = vy*ir; rh.z = vz*ir; rh.w = 0.0f;
    *(float4*)(rhat4 + (size_t)e*4) = rh;

    atomicAdd(&counts[recv[e]], 1);
}

// ---------------- CSR build ----------------
__global__ void k_scan(const int* __restrict__ counts, int* __restrict__ offsets, int N)
{
    __shared__ int wsum[16];
    __shared__ int basev;
    int lane = threadIdx.x & 63;
    int w    = threadIdx.x >> 6;
    if (threadIdx.x == 0) basev = 0;
    __syncthreads();
    for (int start = 0; start < N; start += 1024) {
        int i = start + (int)threadIdx.x;
        int v = (i < N) ? counts[i] : 0;
        int s = v;
        #pragma unroll
        for (int off = 1; off < 64; off <<= 1) {
            int t = __shfl_up(s, off, 64);
            if (lane >= off) s += t;
        }
        if (lane == 63) wsum[w] = s;
        __syncthreads();
        int wbase = 0;
        {
            int ws = (lane < 16) ? wsum[lane] : 0;
            #pragma unroll
            for (int off = 1; off < 16; off <<= 1) {
                int t = __shfl_up(ws, off, 64);
                if (lane >= off) ws += t;
            }
            int excl = __shfl(ws, w - 1, 64);
            wbase = (w == 0) ? 0 : excl;
        }
        if (i < N) offsets[i] = basev + wbase + s - v;   // exclusive
        __syncthreads();
        if (threadIdx.x == 1023) basev += wbase + s;
        __syncthreads();
    }
    if (threadIdx.x == 0) offsets[N] = basev;
}

// scatter + direct permutation-table emission (arrival order within node;
// fp32 reassociation only, ~1e-7 relative — far under threshold margin)
__global__ void k_scatter_perm(const int* __restrict__ recv,
                               const int* __restrict__ offsets,
                               int* __restrict__ cursor,
                               const int* __restrict__ senders,
                               const float* __restrict__ rhat4,
                               int* __restrict__ eslot,      // [E] edge -> slot
                               int* __restrict__ csr_send,   // [E] slot -> sender
                               float* __restrict__ csr_rhat, // [E,4] slot order
                               int E)
{
    int e = blockIdx.x * blockDim.x + threadIdx.x;
    if (e >= E) return;
    int r = recv[e];
    int p = atomicAdd(&cursor[r], 1);
    int slot = offsets[r] + p;
    eslot[e] = slot;
    csr_send[slot] = senders[e];
    *(float4*)(csr_rhat + (size_t)slot*4) = *(const float4*)(rhat4 + (size_t)e*4);
}

// ---------------- radial MLP via MFMA: 32 edges/wave, weight reuse x2 ------
__global__ __launch_bounds__(128) void k_mlp_mfma(
    const uint* __restrict__ rbh,    // [E,4] u32 (8 f16), edge order
    const uint* __restrict__ Wf1, const uint* __restrict__ Wf2,
    const uint* __restrict__ Wf3, const uint* __restrict__ Wf4,
    const int* __restrict__ eslot,   // [E] edge -> CSR slot
    uint* __restrict__ Rpk,          // [2,E,128] u32, rank-interleaved, slot order
    int E, int tiles)                // tiles = ceil(E/32)
{
    __shared__ __align__(16) uint Hl[2][32][132];
    int lane = threadIdx.x & 63;
    int w    = threadIdx.x >> 6;
    int wid  = blockIdx.x * 2 + w;
    if (wid >= 2 * tiles) return;
    int l    = wid / tiles;
    int tile = wid % tiles;
    int e0   = tile * 32;

    uint (*H)[132] = Hl[w];
    int er = lane & 15;
    int kb = lane >> 4;

    f32x4 zero4 = {0.f, 0.f, 0.f, 0.f};

    // ---- stage 1: D = W1^T @ rb (both subtiles) ----
    FU b0, b1;
    b0.u = make_uint4(0,0,0,0);
    b1.u = make_uint4(0,0,0,0);
    if (kb == 0) {
        int ea = e0 + er, eb = e0 + 16 + er;
        if (ea < E) b0.u = *(const uint4*)(rbh + (size_t)ea*4);
        if (eb < E) b1.u = *(const uint4*)(rbh + (size_t)eb*4);
    }
    f32x4 d0[4], d1[4];
    #pragma unroll
    for (int ot = 0; ot < 4; ++ot) {
        FU a;
        a.u = *(const uint4*)(Wf1 + ((size_t)(l*4 + ot)*64 + lane)*4);
        d0[ot] = __builtin_amdgcn_mfma_f32_16x16x32_f16(a.h, b0.h, zero4, 0, 0, 0);
        d1[ot] = __builtin_amdgcn_mfma_f32_16x16x32_f16(a.h, b1.h, zero4, 0, 0, 0);
    }
    #pragma unroll
    for (int ot = 0; ot < 4; ++ot) {
        uint* dA = &H[er][8*ot + 2*kb];
        dA[0] = pack2_f16(silu_f(d0[ot][0]), silu_f(d0[ot][1]));
        dA[1] = pack2_f16(silu_f(d0[ot][2]), silu_f(d0[ot][3]));
        uint* dB = &H[16 + er][8*ot + 2*kb];
        dB[0] = pack2_f16(silu_f(d1[ot][0]), silu_f(d1[ot][1]));
        dB[1] = pack2_f16(silu_f(d1[ot][2]), silu_f(d1[ot][3]));
    }

    // ---- stages 2,3: D = W^T @ H ----
    const uint* Wfs[2] = { Wf2, Wf3 };
    #pragma unroll
    for (int s = 0; s < 2; ++s) {
        FU hA0, hA1, hB0, hB1;
        hA0.u = *(const uint4*)&H[er][4*kb];
        hA1.u = *(const uint4*)&H[er][16 + 4*kb];
        hB0.u = *(const uint4*)&H[16 + er][4*kb];
        hB1.u = *(const uint4*)&H[16 + er][16 + 4*kb];
        #pragma unroll
        for (int ot = 0; ot < 4; ++ot) {
            FU a;
            a.u = *(const uint4*)(Wfs[s] + ((size_t)((l*4 + ot)*2 + 0)*64 + lane)*4);
            d0[ot] = __builtin_amdgcn_mfma_f32_16x16x32_f16(a.h, hA0.h, zero4, 0, 0, 0);
            d1[ot] = __builtin_amdgcn_mfma_f32_16x16x32_f16(a.h, hB0.h, zero4, 0, 0, 0);
            a.u = *(const uint4*)(Wfs[s] + ((size_t)((l*4 + ot)*2 + 1)*64 + lane)*4);
            d0[ot] = __builtin_amdgcn_mfma_f32_16x16x32_f16(a.h, hA1.h, d0[ot], 0, 0, 0);
            d1[ot] = __builtin_amdgcn_mfma_f32_16x16x32_f16(a.h, hB1.h, d1[ot], 0, 0, 0);
        }
        #pragma unroll
        for (int ot = 0; ot < 4; ++ot) {
            uint* dA = &H[er][8*ot + 2*kb];
            dA[0] = pack2_f16(silu_f(d0[ot][0]), silu_f(d0[ot][1]));
            dA[1] = pack2_f16(silu_f(d0[ot][2]), silu_f(d0[ot][3]));
            uint* dB = &H[16 + er][8*ot + 2*kb];
            dB[0] = pack2_f16(silu_f(d1[ot][0]), silu_f(d1[ot][1]));
            dB[1] = pack2_f16(silu_f(d1[ot][2]), silu_f(d1[ot][3]));
        }
    }

    // ---- stage 4: R = W4^T @ H; rank-interleaved; flush to CSR slots ----
    FU hA0, hA1, hB0, hB1;
    hA0.u = *(const uint4*)&H[er][4*kb];
    hA1.u = *(const uint4*)&H[er][16 + 4*kb];
    hB0.u = *(const uint4*)&H[16 + er][4*kb];
    hB1.u = *(const uint4*)&H[16 + er][16 + 4*kb];
    #pragma unroll
    for (int ri = 0; ri < 4; ++ri) {
        #pragma unroll
        for (int otl = 0; otl < 4; ++otl) {
            int ot = ri*4 + otl;
            FU a;
            f32x4 dA, dB;
            a.u = *(const uint4*)(Wf4 + ((size_t)((l*16 + ot)*2 + 0)*64 + lane)*4);
            dA = __builtin_amdgcn_mfma_f32_16x16x32_f16(a.h, hA0.h, zero4, 0, 0, 0);
            dB = __builtin_amdgcn_mfma_f32_16x16x32_f16(a.h, hB0.h, zero4, 0, 0, 0);
            a.u = *(const uint4*)(Wf4 + ((size_t)((l*16 + ot)*2 + 1)*64 + lane)*4);
            dA = __builtin_amdgcn_mfma_f32_16x16x32_f16(a.h, hA1.h, dA, 0, 0, 0);
            dB = __builtin_amdgcn_mfma_f32_16x16x32_f16(a.h, hB1.h, dB, 0, 0, 0);
            int p = otl*8 + kb*2;
            H[er][(p  )*4 + ri] = pack2_f16(dA[0], dA[1]);
            H[er][(p+1)*4 + ri] = pack2_f16(dA[2], dA[3]);
            H[16 + er][(p  )*4 + ri] = pack2_f16(dB[0], dB[1]);
            H[16 + er][(p+1)*4 + ri] = pack2_f16(dB[2], dB[3]);
        }
    }
    #pragma unroll
    for (int it = 0; it < 16; ++it) {
        int f   = it*64 + lane;
        int row = f >> 5;
        int q4  = (f & 31) * 4;
        int eg  = e0 + row;
        if (eg < E) {
            int slot = eslot[eg];
            *(uint4*)(Rpk + ((size_t)l*E + slot)*128 + q4) = *(const uint4*)&H[row][q4];
        }
    }
}

// ---------------- node gather + contraction + mix + readout ----------------
__global__ __launch_bounds__(256) void k_node(
    const uint*  __restrict__ Rpk,     // [E,128] u32 this layer, slot order
    const float* __restrict__ h0,      // [N,64]
    const int*   __restrict__ csr_send,// [E] slot -> sender
    const float* __restrict__ csr_rhat,// [E,4] slot order
    const int*   __restrict__ offsets, // [N+1]
    const float* __restrict__ mixw,    // [4,64,64] (this layer)
    const float* __restrict__ readw,   // [64]      (this layer)
    float* __restrict__ h0n,           // [N,64]
    const float* __restrict__ eprev,   // [N] or null
    float* __restrict__ eout,          // [N]
    int N)
{
    int gtid = blockIdx.x * blockDim.x + threadIdx.x;
    int wave = gtid >> 6;
    int lane = threadIdx.x & 63;
    int w    = threadIdx.x >> 6;
    __shared__ float Bl[4][4][64];
    bool active = (wave < N);
    int n = active ? wave : 0;
    int half  = lane & 1;
    int cpair = lane >> 1;

    float a0 = 0.f;
    float a1[3]  = {0.f,0.f,0.f};
    float a2[6]  = {0.f,0.f,0.f,0.f,0.f,0.f};
    float a3[10] = {0.f,0.f,0.f,0.f,0.f,0.f,0.f,0.f,0.f,0.f};

    auto accum = [&](float x, float y, float z, float hj, uint4 qv) {
        float t0 = unpk_f16(qv.x, half) * hj;
        float t1 = unpk_f16(qv.y, half) * hj;
        float t2 = unpk_f16(qv.z, half) * hj;
        float t3 = unpk_f16(qv.w, half) * hj;
        a0 += t0;
        a1[0] = fmaf(t1, x, a1[0]);
        a1[1] = fmaf(t1, y, a1[1]);
        a1[2] = fmaf(t1, z, a1[2]);
        float qxx = x*x, qxy = x*y, qxz = x*z, qyy = y*y, qyz = y*z, qzz = z*z;
        a2[0] = fmaf(t2, qxx, a2[0]);
        a2[1] = fmaf(t2, qxy, a2[1]);
        a2[2] = fmaf(t2, qxz, a2[2]);
        a2[3] = fmaf(t2, qyy, a2[3]);
        a2[4] = fmaf(t2, qyz, a2[4]);
        a2[5] = fmaf(t2, qzz, a2[5]);
        float u0 = t3*qxx, u1 = t3*qxy, u3 = t3*qyy, u5 = t3*qzz;
        a3[0] = fmaf(u0, x, a3[0]);
        a3[1] = fmaf(u0, y, a3[1]);
        a3[2] = fmaf(u0, z, a3[2]);
        a3[3] = fmaf(u3, x, a3[3]);
        a3[4] = fmaf(u1, z, a3[4]);
        a3[5] = fmaf(u5, x, a3[5]);
        a3[6] = fmaf(u3, y, a3[6]);
        a3[7] = fmaf(u3, z, a3[7]);
        a3[8] = fmaf(u5, y, a3[8]);
        a3[9] = fmaf(u5, z, a3[9]);
    };

    if (active) {
        int beg = __builtin_amdgcn_readfirstlane(offsets[n]);
        int end = __builtin_amdgcn_readfirstlane(offsets[n+1]);
        int i = beg;
        for (; i + 4 <= end; i += 4) {
            int sn_[4]; float4 rh_[4]; float hj_[4]; uint4 q_[4];
            #pragma unroll
            for (int k = 0; k < 4; ++k) sn_[k] = csr_send[i+k];
            #pragma unroll
            for (int k = 0; k < 4; ++k) {
                rh_[k] = *(const float4*)(csr_rhat + (size_t)(i+k)*4);
                q_[k]  = *(const uint4*)(Rpk + (size_t)(i+k)*128 + cpair*4);
            }
            #pragma unroll
            for (int k = 0; k < 4; ++k) hj_[k] = h0[(size_t)sn_[k]*64 + lane];
            #pragma unroll
            for (int k = 0; k < 4; ++k)
                accum(rh_[k].x, rh_[k].y, rh_[k].z, hj_[k], q_[k]);
        }
        for (; i < end; ++i) {
            int snd = csr_send[i];
            float4 rh = *(const float4*)(csr_rhat + (size_t)i*4);
            uint4  qv = *(const uint4*)(Rpk + (size_t)i*128 + cpair*4);
            float  hj = h0[(size_t)snd*64 + lane];
            accum(rh.x, rh.y, rh.z, hj, qv);
        }
    }

    // invariants: B_r = (2r+1)/256 * sum over full tensor (multiplicity wts)
    float B0 = a0 * 0.0625f;
    float s1 = a1[0]*a1[0] + a1[1]*a1[1] + a1[2]*a1[2];
    float B1 = s1 * (3.0f/256.0f);
    float s2 = a2[0]*a2[0] + a2[3]*a2[3] + a2[5]*a2[5]
             + 2.0f*(a2[1]*a2[1] + a2[2]*a2[2] + a2[4]*a2[4]);
    float B2 = s2 * (5.0f/256.0f);
    float s3 = a3[0]*a3[0] + a3[6]*a3[6] + a3[9]*a3[9]
             + 3.0f*(a3[1]*a3[1] + a3[2]*a3[2] + a3[3]*a3[3]
                   + a3[5]*a3[5] + a3[7]*a3[7] + a3[8]*a3[8])
             + 6.0f*a3[4]*a3[4];
    float B3 = s3 * (7.0f/256.0f);

    Bl[w][0][lane] = B0;
    Bl[w][1][lane] = B1;
    Bl[w][2][lane] = B2;
    Bl[w][3][lane] = B3;
    __syncthreads();

    if (active) {
        float acc = 0.0f;
        for (int ri = 0; ri < 4; ++ri) {
            #pragma unroll 8
            for (int j = 0; j < 64; ++j)
                acc = fmaf(Bl[w][ri][j], mixw[(ri*64 + j)*64 + lane], acc);
        }
        h0n[(size_t)n*64 + lane] = acc;

        float evl = acc * readw[lane];
        #pragma unroll
        for (int off = 1; off < 64; off <<= 1) evl += __shfl_xor(evl, off, 64);
        if (lane == 0) {
            float o = evl;
            if (eprev) o += eprev[n];
            eout[n] = o;
        }
    }
}

// ---------------------------------------------------------------------------
extern "C" void kernel_launch(void* const* d_in, const int* in_sizes, int n_in,
                              void* d_out, int out_size, void* d_ws, size_t ws_size,
                              hipStream_t stream)
{
    const int*   species   = (const int*)  d_in[0];
    const int*   senders   = (const int*)  d_in[1];
    const int*   receivers = (const int*)  d_in[2];
    const float* edge_vec  = (const float*)d_in[3];
    const float* embed_w   = (const float*)d_in[4];
    const float* rad_w1    = (const float*)d_in[5];
    const float* rad_w2    = (const float*)d_in[6];
    const float* rad_w3    = (const float*)d_in[7];
    const float* rad_w4    = (const float*)d_in[8];
    const float* mix_w     = (const float*)d_in[9];
    const float* read_w    = (const float*)d_in[10];

    int N = in_sizes[0];
    int E = in_sizes[1];
    float* out = (float*)d_out;

    char* ws = (char*)d_ws;
    size_t off = 0;
    auto alloc = [&](size_t bytes) -> char* {
        char* p = ws + off;
        off = (off + bytes + 255) & ~(size_t)255;
        return p;
    };
    uint*  rbh     = (uint*) alloc((size_t)E*4*sizeof(uint));
    float* rhat4   = (float*)alloc((size_t)E*4*sizeof(float));
    float* h0a     = (float*)alloc((size_t)N*64*sizeof(float));
    float* h0b     = (float*)alloc((size_t)N*64*sizeof(float));
    float* ener    = (float*)alloc((size_t)N*sizeof(float));
    int* counts    = (int*)alloc((size_t)N*sizeof(int));
    int* offsets   = (int*)alloc((size_t)(N+1)*sizeof(int));
    int* cursor    = (int*)alloc((size_t)N*sizeof(int));
    int* eslot     = (int*)alloc((size_t)E*sizeof(int));
    int* csr_send  = (int*)alloc((size_t)E*sizeof(int));
    float* csr_rhat= (float*)alloc((size_t)E*4*sizeof(float));
    uint* Wf1      = (uint*)alloc(2048*sizeof(uint));
    uint* Wf2      = (uint*)alloc(4096*sizeof(uint));
    uint* Wf3      = (uint*)alloc(4096*sizeof(uint));
    uint* Wf4      = (uint*)alloc(16384*sizeof(uint));
    uint* Rpk      = (uint*)alloc((size_t)2*E*128*sizeof(uint));

    int NC = N * 64;
    k_setup<<<(NC + 255)/256, 256, 0, stream>>>(
        rad_w1, rad_w2, rad_w3, rad_w4, Wf1, Wf2, Wf3, Wf4,
        species, embed_w, h0a, counts, cursor, N, NC);

    k_edge_basis<<<(E + 255)/256, 256, 0, stream>>>(
        edge_vec, receivers, rbh, rhat4, counts, E);
    k_scan<<<1, 1024, 0, stream>>>(counts, offsets, N);
    k_scatter_perm<<<(E + 255)/256, 256, 0, stream>>>(
        receivers, offsets, cursor, senders, rhat4, eslot, csr_send, csr_rhat, E);

    int tiles = (E + 31) / 32;
    int waves = 2 * tiles;
    k_mlp_mfma<<<(waves + 1)/2, 128, 0, stream>>>(
        rbh, Wf1, Wf2, Wf3, Wf4, eslot, Rpk, E, tiles);

    float* hcur = h0a;
    float* hnxt = h0b;
    for (int l = 0; l < 2; ++l) {
        uint* Rl = Rpk + (size_t)l * E * 128;
        k_node<<<((size_t)N*64 + 255)/256, 256, 0, stream>>>(
            Rl, hcur, csr_send, csr_rhat, offsets,
            mix_w + (size_t)l*4*64*64,
            read_w + (size_t)l*64,
            hnxt,
            (l == 0) ? nullptr : ener,
            (l == 0) ? ener : out,
            N);
        float* tmp = hcur; hcur = hnxt; hnxt = tmp;
    }
}